// Round 6
// baseline (369.152 us; speedup 1.0000x reference)
//
#include <hip/hip_runtime.h>

#ifndef __has_builtin
#define __has_builtin(x) 0
#endif

__device__ __forceinline__ float fast_exp2(float x) {
#if __has_builtin(__builtin_amdgcn_exp2f)
    return __builtin_amdgcn_exp2f(x);
#else
    return exp2f(x);
#endif
}

// Canonical CDNA wave64 sum via DPP (VALU pipe, not DS):
// row_shr 1/2/4/8 (bound_ctrl: invalid->0), then row_bcast15 (rows 1,3),
// row_bcast31 (rows 2,3). Lane 63 ends with the full 64-lane sum.
__device__ __forceinline__ float wave_sum_dpp(float x) {
    int v;
    v = __builtin_amdgcn_update_dpp(0, __float_as_int(x), 0x111, 0xf, 0xf, true);
    x += __int_as_float(v);
    v = __builtin_amdgcn_update_dpp(0, __float_as_int(x), 0x112, 0xf, 0xf, true);
    x += __int_as_float(v);
    v = __builtin_amdgcn_update_dpp(0, __float_as_int(x), 0x114, 0xf, 0xf, true);
    x += __int_as_float(v);
    v = __builtin_amdgcn_update_dpp(0, __float_as_int(x), 0x118, 0xf, 0xf, true);
    x += __int_as_float(v);
    v = __builtin_amdgcn_update_dpp(0, __float_as_int(x), 0x142, 0xa, 0xf, false);
    x += __int_as_float(v);
    v = __builtin_amdgcn_update_dpp(0, __float_as_int(x), 0x143, 0xc, 0xf, false);
    x += __int_as_float(v);
    return x;
}

// Block-wide barrier WITHOUT the vmcnt(0) drain that __syncthreads emits.
// Only LDS ops (sP/sInvD) need visibility across the barrier; in-flight
// global prefetch loads (read-only, into private VGPRs) legally stay
// outstanding, overlapping part k+1's HBM reads with part k's compute.
__device__ __forceinline__ void sync_lds() {
    asm volatile("s_waitcnt lgkmcnt(0)" ::: "memory");
    __builtin_amdgcn_s_barrier();
    asm volatile("" ::: "memory");
}

constexpr int   kB      = 256;
constexpr int   kC      = 1024;
constexpr int   kG      = 13;
constexpr int   kP      = kG * kG;                // 169
constexpr int   kRP     = 13;                     // positions per part = one row
constexpr float kEps    = 1e-6f;
constexpr float kZ      = 17.079468445347132f;    // 2*pi*e
constexpr float kLog2e  = 1.4426950408889634f;
constexpr float kInv169 = 1.0f / 169.0f;
constexpr float kScale  = 1.0f / (256.0f * 1024.0f);

// One pipelined row step. PART (= grid row h) is compile-time; LAST part
// skips the prefetch. cur holds raw x for row PART; nxt receives the
// prefetch of row PART+1. Position accumulation order is ascending and
// op-for-op identical to the verified R2..R5 kernels -> absmax stays 0.
template<int PART, bool LAST>
__device__ __forceinline__ void do_row(
    const float* __restrict__ xb, int tid, int lane, int wid,
    float (&cur)[kRP], float (&nxt)[kRP],
    float& S0, float& S1x, float& S1y, float& S2x, float& S2y,
    float* __restrict__ sP, float* __restrict__ sInvD)
{
    constexpr int START = PART * kRP;

    // 1) prefetch next row (completion awaited only at next part's exp)
    if (!LAST) {
        const float* __restrict__ xn = xb + (size_t)(START + kRP) * kC + tid;
        #pragma unroll
        for (int i = 0; i < kRP; ++i)
            nxt[i] = xn[(size_t)i * kC];
    }

    // 2) exp (waits only on cur's loads, issued one part earlier)
    #pragma unroll
    for (int i = 0; i < kRP; ++i)
        cur[i] = fast_exp2(cur[i] * kLog2e);

    // 3) per-position wave partial sums on the VALU pipe
    #pragma unroll
    for (int i = 0; i < kRP; ++i) {
        const float s = wave_sum_dpp(cur[i]);
        if (lane == 63) sP[i * 16 + wid] = s;
    }
    sync_lds();

    // 4) 16-way cross-wave tree -> per-position inverse denominator
    if (tid < kRP) {
        float d = 0.f;
        #pragma unroll
        for (int w = 0; w < 16; ++w)
            d += sP[tid * 16 + w];
        sInvD[tid] = 1.0f / (d + 1e-30f);
    }
    sync_lds();

    // 5) stats: h = PART constant, w = i. Same fmaf sequence/values as the
    //    verified kernels (fx=(float)(h+1), fy=(float)(w+1)).
    const float fx = (float)(PART + 1);
    #pragma unroll
    for (int i = 0; i < kRP; ++i) {
        const float f  = cur[i] * sInvD[i];
        const float fy = (float)(i + 1);
        S0  += f;
        S1x  = fmaf(fx,      f, S1x);
        S1y  = fmaf(fy,      f, S1y);
        S2x  = fmaf(fx * fx, f, S2x);
        S2y  = fmaf(fy * fy, f, S2y);
    }
    // sP/sInvD reuse across parts is race-free: writes for part k+1 happen
    // only after every wave passed barrier2 of part k (so the tree reader
    // and all sInvD consumers of part k are done).
}

// ---------------------------------------------------------------------------
// Fully fused, software-pipelined kernel: one block per batch b, 1024
// threads (thread = channel). 13 parts of 13 positions (one grid row each),
// double-buffered e-regs (13+13), raw lgkm-only barriers so prefetch global
// loads stay in flight across barriers.
//
// amdgpu_waves_per_eu(4,4): grid = 256 blocks = 1 block/CU, so occupancy
// above 16 waves/CU (4/EU) can never materialize. Without the MAX bound the
// backend targets the theoretical 8 waves/EU and caps VGPRs at 64
// (R0-R5 all measured VGPR_Count=64), demoting the e-buffers to scratch:
// WRITE_SIZE ~236 MB = 924 B/thread of spill traffic, kernel 204 us.
// Pinning min=max=4 raises the budget to 128 VGPRs (16 waves x 128 = full
// 2048-entry pool, still launchable); the ~60-reg body fits spill-free.
// ---------------------------------------------------------------------------
__global__ __launch_bounds__(1024)
__attribute__((amdgpu_waves_per_eu(4, 4)))
void fused_kernel(const float* __restrict__ x, float* __restrict__ out)
{
    __shared__ float sP[kRP * 16];        // per-(position, wave) partials
    __shared__ float sInvD[kRP];
    __shared__ float sred[16];

    const int tid  = threadIdx.x;
    const int lane = tid & 63;
    const int wid  = tid >> 6;
    const int b    = blockIdx.x;

    const float* __restrict__ xb = x + (size_t)b * kP * kC;

    float e0[kRP], e1[kRP];
    float S0 = 0.f, S1x = 0.f, S1y = 0.f, S2x = 0.f, S2y = 0.f;

    // prologue: load row 0
    {
        const float* __restrict__ xc = xb + tid;
        #pragma unroll
        for (int i = 0; i < kRP; ++i)
            e0[i] = xc[(size_t)i * kC];
    }

    do_row< 0, false>(xb, tid, lane, wid, e0, e1, S0, S1x, S1y, S2x, S2y, sP, sInvD);
    do_row< 1, false>(xb, tid, lane, wid, e1, e0, S0, S1x, S1y, S2x, S2y, sP, sInvD);
    do_row< 2, false>(xb, tid, lane, wid, e0, e1, S0, S1x, S1y, S2x, S2y, sP, sInvD);
    do_row< 3, false>(xb, tid, lane, wid, e1, e0, S0, S1x, S1y, S2x, S2y, sP, sInvD);
    do_row< 4, false>(xb, tid, lane, wid, e0, e1, S0, S1x, S1y, S2x, S2y, sP, sInvD);
    do_row< 5, false>(xb, tid, lane, wid, e1, e0, S0, S1x, S1y, S2x, S2y, sP, sInvD);
    do_row< 6, false>(xb, tid, lane, wid, e0, e1, S0, S1x, S1y, S2x, S2y, sP, sInvD);
    do_row< 7, false>(xb, tid, lane, wid, e1, e0, S0, S1x, S1y, S2x, S2y, sP, sInvD);
    do_row< 8, false>(xb, tid, lane, wid, e0, e1, S0, S1x, S1y, S2x, S2y, sP, sInvD);
    do_row< 9, false>(xb, tid, lane, wid, e1, e0, S0, S1x, S1y, S2x, S2y, sP, sInvD);
    do_row<10, false>(xb, tid, lane, wid, e0, e1, S0, S1x, S1y, S2x, S2y, sP, sInvD);
    do_row<11, false>(xb, tid, lane, wid, e1, e0, S0, S1x, S1y, S2x, S2y, sP, sInvD);
    do_row<12, true >(xb, tid, lane, wid, e0, e1, S0, S1x, S1y, S2x, S2y, sP, sInvD);

    // det epilogue per (b, c) and block-wide mean contribution
    const float s   = S0 + kEps;
    const float is  = 1.0f / s;
    const float mx  = S1x * is;
    const float my  = S1y * is;
    const float nx  = S2x - mx * (2.0f * S1x - mx * S0);
    const float ny  = S2y - my * (2.0f * S1y - my * S0);
    const float t   = (nx + ny) * is * kInv169;
    float det = t * t * kZ;

    #pragma unroll
    for (int m = 1; m < 64; m <<= 1)
        det += __shfl_xor(det, m);

    if (lane == 0) sred[wid] = det;
    __syncthreads();
    if (wid == 0) {
        float v = (lane < 16) ? sred[lane] : 0.0f;
        #pragma unroll
        for (int m = 1; m < 16; m <<= 1)
            v += __shfl_xor(v, m);
        if (lane == 0) atomicAdd(out, v * kScale);
    }
}

extern "C" void kernel_launch(void* const* d_in, const int* in_sizes, int n_in,
                              void* d_out, int out_size, void* d_ws, size_t ws_size,
                              hipStream_t stream)
{
    const float* x   = (const float*)d_in[0];
    float*       out = (float*)d_out;

    // out is tiny (scalar compare); R1->R2 delta proved this memset is ~free.
    hipMemsetAsync(out, 0, sizeof(float) * (size_t)out_size, stream);
    fused_kernel<<<dim3(kB), dim3(1024), 0, stream>>>(x, out);
}